// Round 3
// baseline (1451.212 us; speedup 1.0000x reference)
//
#include <hip/hip_runtime.h>
#include <hip/hip_bf16.h>
#include <math.h>

#define B_ 128
#define L_ 128
#define N_ 6
#define FA_ 39
#define FB_ 10
#define D_ 200
#define MB_ 256
#define R_ 3
#define T_ 2
#define NEGV -9e8f
#define BL_ (B_*L_)        // 16384
#define BLD_ (BL_*D_)      // 3276800
#define G3D_ (3*D_)        // 600
#define FP32TAG 0x3F800000u

typedef __hip_bfloat16 bf16;

__device__ __forceinline__ float b2f(const bf16 x){ return __bfloat162float(x); }
__device__ __forceinline__ float lreluf(float x){ return x>=0.f ? x : 0.01f*x; }
__device__ __forceinline__ float eluf(float x){ return x>0.f ? x : expm1f(x); }
__device__ __forceinline__ float sigmf(float x){ return 1.f/(1.f+expf(-x)); }

#define NSEG 25
struct CvtArgs { const void* src[NSEG]; int ofs[NSEG+1]; };

// canonicalize all float inputs (bf16 OR fp32 storage) to fp32 in ws
__global__ void k_convert(CvtArgs c, float* __restrict__ dst, const unsigned* __restrict__ amtag, int total){
    int i = blockIdx.x*blockDim.x + threadIdx.x;
    if (i >= total) return;
    bool f32 = (*amtag == FP32TAG);
    int s = 0;
    while (i >= c.ofs[s+1]) s++;
    int j = i - c.ofs[s];
    dst[i] = f32 ? ((const float*)c.src[s])[j] : b2f(((const bf16*)c.src[s])[j]);
}

// transpose GRU weights to [r][k][j] fp32 for coalesced gate-GEMM loads (dual-dtype read)
__global__ void k_transpose(const void* __restrict__ Wih, const void* __restrict__ Whh,
                            float* __restrict__ Ti, float* __restrict__ Th,
                            const unsigned* __restrict__ amtag){
    int idx = blockIdx.x*blockDim.x + threadIdx.x;
    if (idx >= R_*D_*G3D_) return;       // 360000
    bool f32 = (*amtag == FP32TAG);
    int j  = idx % G3D_;
    int rk = idx / G3D_;
    int k  = rk % D_;
    int r  = rk / D_;
    size_t si = ((size_t)r*G3D_ + j)*D_ + k;
    Ti[idx] = f32 ? ((const float*)Wih)[si] : b2f(((const bf16*)Wih)[si]);
    Th[idx] = f32 ? ((const float*)Whh)[si] : b2f(((const bf16*)Whh)[si]);
}

// atom_feature = lrelu(atom_list @ W_atom + b_atom); h = cur = atom_feature
__global__ void k_atomfeat(const float* __restrict__ atom_list, const float* __restrict__ W_atom,
                           const float* __restrict__ b_atom, float* __restrict__ h, float* __restrict__ cur){
    int idx = blockIdx.x*blockDim.x + threadIdx.x;
    if (idx >= BLD_) return;
    int d = idx % D_;
    int al = idx / D_;
    const float* arow = atom_list + (size_t)al*FA_;
    float acc = b_atom[d];
    for (int k=0;k<FA_;k++) acc += arow[k] * W_atom[k*D_ + d];
    float v = lreluf(acc);
    h[idx] = v; cur[idx] = v;
}

// per-atom dots with W_align[r]: s1 = cur . Wa[0:D], tb = cur . Wa[D:2D]
__global__ void k_dots(const float* __restrict__ cur, const float* __restrict__ W_align, int r,
                       float* __restrict__ s1, float* __restrict__ tb){
    int wave = (blockIdx.x*blockDim.x + threadIdx.x) >> 6;
    int lane = threadIdx.x & 63;
    if (wave >= BL_) return;
    const float* Wa = W_align + r*2*D_;
    const float* row = cur + (size_t)wave*D_;
    float a1 = 0.f, a2 = 0.f;
    for (int k=lane; k<D_; k+=64){
        float c = row[k];
        a1 += c * Wa[k];
        a2 += c * Wa[D_+k];
    }
    for (int o=32;o>0;o>>=1){ a1 += __shfl_xor(a1,o); a2 += __shfl_xor(a2,o); }
    if (lane==0){ s1[wave]=a1; tb[wave]=a2; }
}

// fused: (round-0 on-the-fly neighbor features) + attention softmax + weighted sum + ctx GEMM
// one wave (64 threads) per atom
__global__ void __launch_bounds__(64) k_attn_ctx(
        const float* __restrict__ cur, const float* __restrict__ s1, const float* __restrict__ tb,
        const int* __restrict__ adl, const int* __restrict__ bdl,
        const float* __restrict__ atom_list, const float* __restrict__ bond_list,
        const float* __restrict__ W_nei, const float* __restrict__ b_nei,
        const float* __restrict__ W_align, const float* __restrict__ b_align,
        const float* __restrict__ W_attend, const float* __restrict__ b_attend, int r,
        float* __restrict__ ctx){
    int al = blockIdx.x;
    int lane = threadIdx.x;
    int bi = al >> 7;            // / L_
    __shared__ float s_nei[N_][D_];
    __shared__ float s_wnei[D_];
    __shared__ float s_s2[N_];

    int idxn[N_]; bool pad[N_];
    for (int n=0;n<N_;n++){ idxn[n] = adl[al*N_ + n]; pad[n] = (idxn[n] == L_-1); }

    if (r == 0){
        for (int j = lane; j < N_*D_; j += 64){
            int n = j / D_, d = j - n*D_;
            int a  = idxn[n];
            int bd = bdl[al*N_ + n];
            const float* arow = atom_list + ((size_t)bi*L_ + a)*FA_;
            const float* brow = bond_list + ((size_t)bi*MB_ + bd)*FB_;
            float acc = b_nei[d];
            for (int k=0;k<FA_;k++) acc += arow[k] * W_nei[k*D_ + d];
            for (int k=0;k<FB_;k++) acc += brow[k] * W_nei[(FA_+k)*D_ + d];
            s_nei[n][d] = lreluf(acc);
        }
        __syncthreads();
        const float* Wab = W_align + (2*r+1)*D_;   // bottom half of W_align[r]
        for (int n=0;n<N_;n++){
            float acc = 0.f;
            for (int d=lane; d<D_; d+=64) acc += s_nei[n][d] * Wab[d];
            for (int o=32;o>0;o>>=1) acc += __shfl_xor(acc,o);
            if (lane==0) s_s2[n] = acc;
        }
        __syncthreads();
    } else {
        if (lane < N_) s_s2[lane] = tb[bi*L_ + idxn[lane]];
        __syncthreads();
    }

    float s1v = s1[al];
    float bav = b_align[r];
    float a[N_]; float mx = -1e30f;
    for (int n=0;n<N_;n++){
        float v = lreluf(s1v + s_s2[n] + bav);
        if (pad[n]) v += NEGV;
        a[n] = v; mx = fmaxf(mx, v);
    }
    float w[N_]; float se = 0.f;
    for (int n=0;n<N_;n++){ float e = expf(a[n]-mx); w[n]=e; se += e; }
    float inv = 1.f/se; float wsv = 0.f;
    for (int n=0;n<N_;n++){ w[n] = pad[n] ? 0.f : w[n]*inv; wsv += w[n]; }

    if (r == 0){
        for (int d=lane; d<D_; d+=64){
            float acc = 0.f;
            for (int n=0;n<N_;n++) acc += w[n] * s_nei[n][d];
            s_wnei[d] = acc;
        }
    } else {
        for (int d=lane; d<D_; d+=64){
            float acc = 0.f;
            for (int n=0;n<N_;n++) acc += w[n] * cur[((size_t)bi*L_ + idxn[n])*D_ + d];
            s_wnei[d] = acc;
        }
    }
    __syncthreads();

    // ctx = elu(wnei @ W_attend[r] + wsum * b_attend[r])
    const float* W = W_attend + (size_t)r*D_*D_;
    for (int d=lane; d<D_; d+=64){
        float acc = wsv * b_attend[r*D_ + d];
        for (int k=0;k<D_;k++) acc += s_wnei[k] * W[k*D_ + d];
        ctx[(size_t)al*D_ + d] = eluf(acc);
    }
}

// fused GRU: gates GEMM (transposed weights) + combine. 8 atoms per 256-thread block.
__global__ void __launch_bounds__(256) k_gruf(const float* __restrict__ ctx, float* __restrict__ h,
        float* __restrict__ cur,
        const float* __restrict__ Ti, const float* __restrict__ Th,
        const float* __restrict__ bih, const float* __restrict__ bhh, int r){
    int tid = threadIdx.x;
    int al0 = blockIdx.x * 8;
    __shared__ float s_x[8][D_], s_h[8][D_];
    __shared__ float s_gi[8][G3D_], s_gh[8][G3D_];
    for (int i = tid; i < 8*D_; i += 256){
        int a = i / D_, d = i - a*D_;
        s_x[a][d] = ctx[(size_t)(al0+a)*D_ + d];
        s_h[a][d] = h[(size_t)(al0+a)*D_ + d];
    }
    __syncthreads();
    const float* ti = Ti + (size_t)r*D_*G3D_;
    const float* th = Th + (size_t)r*D_*G3D_;
    for (int j = tid; j < G3D_; j += 256){
        float ai[8], ah[8];
        float bi_ = bih[r*G3D_+j], bh_ = bhh[r*G3D_+j];
        #pragma unroll
        for (int a=0;a<8;a++){ ai[a]=bi_; ah[a]=bh_; }
        for (int k=0;k<D_;k++){
            float wiv = ti[(size_t)k*G3D_ + j];
            float whv = th[(size_t)k*G3D_ + j];
            #pragma unroll
            for (int a=0;a<8;a++){ ai[a] += s_x[a][k]*wiv; ah[a] += s_h[a][k]*whv; }
        }
        #pragma unroll
        for (int a=0;a<8;a++){ s_gi[a][j]=ai[a]; s_gh[a][j]=ah[a]; }
    }
    __syncthreads();
    for (int i = tid; i < 8*D_; i += 256){
        int a = i / D_, d = i - a*D_;
        float rr = sigmf(s_gi[a][d] + s_gh[a][d]);
        float zz = sigmf(s_gi[a][D_+d] + s_gh[a][D_+d]);
        float nn = tanhf(s_gi[a][2*D_+d] + rr*s_gh[a][2*D_+d]);
        float hv = s_h[a][d];
        float hn = (1.f-zz)*nn + zz*hv;
        h[(size_t)(al0+a)*D_+d] = hn;
        cur[(size_t)(al0+a)*D_+d] = fmaxf(hn, 0.f);
    }
}

__device__ __forceinline__ float blockReduceSum(float v, float* s_red){
    for (int o=32;o>0;o>>=1) v += __shfl_xor(v,o);
    int lane = threadIdx.x & 63, wid = threadIdx.x >> 6;
    __syncthreads();
    if (lane==0) s_red[wid] = v;
    __syncthreads();
    float r = s_red[0];
    int nw = blockDim.x >> 6;
    for (int i=1;i<nw;i++) r += s_red[i];
    return r;
}

// molecule phase: pooling, T mol-attention+GRU steps, output head. One block per molecule.
__global__ void __launch_bounds__(256) k_mol(const float* __restrict__ cur, const float* __restrict__ atom_mask,
    const float* __restrict__ Wma, const float* __restrict__ bma,
    const float* __restrict__ Wmt, const float* __restrict__ bmt,
    const float* __restrict__ mWih, const float* __restrict__ mWhh,
    const float* __restrict__ mbih, const float* __restrict__ mbhh,
    const float* __restrict__ Wme, const float* __restrict__ bme,
    const float* __restrict__ Wout, const float* __restrict__ bout,
    void* __restrict__ out, const unsigned* __restrict__ amtag){
    int b = blockIdx.x, tid = threadIdx.x;
    __shared__ float s_am[L_], s_neg[L_], s_mf[D_], s_act[D_], s_sc[L_], s_w[L_];
    __shared__ float s_wc[D_], s_ctx[D_], s_gi[G3D_], s_gh[G3D_], s_red[8];
    const float* curb = cur + (size_t)b*L_*D_;
    if (tid < L_){
        float am = atom_mask[b*L_ + tid];
        s_am[tid] = am;
        s_neg[tid] = (am == 0.f) ? NEGV : 0.f;
    }
    __syncthreads();
    for (int d=tid; d<D_; d+=256){
        float acc = 0.f;
        for (int l=0;l<L_;l++) acc += curb[l*D_ + d] * s_am[l];
        s_mf[d] = acc; s_act[d] = fmaxf(acc, 0.f);
    }
    __syncthreads();
    for (int t=0;t<T_;t++){
        float p = 0.f;
        for (int d=tid; d<D_; d+=256) p += s_act[d] * Wma[d];
        float s1 = blockReduceSum(p, s_red);
        if (tid < L_){
            const float* row = curb + tid*D_;
            float sc = 0.f;
            for (int d=0; d<D_; d++) sc += row[d] * Wma[D_+d];
            sc = lreluf(s1 + sc + bma[0]);
            s_sc[tid] = sc + s_neg[tid];
        }
        __syncthreads();
        if (tid==0){ float mx=-1e30f; for (int l=0;l<L_;l++) mx=fmaxf(mx,s_sc[l]); s_red[4]=mx; }
        __syncthreads();
        if (tid < L_) s_w[tid] = expf(s_sc[tid] - s_red[4]);
        __syncthreads();
        if (tid==0){ float sm=0.f; for (int l=0;l<L_;l++) sm+=s_w[l]; s_red[5]=sm; }
        __syncthreads();
        if (tid < L_) s_w[tid] = s_w[tid]/s_red[5]*s_am[tid];
        __syncthreads();
        if (tid==0){ float sm=0.f; for (int l=0;l<L_;l++) sm+=s_w[l]; s_red[6]=sm; }
        __syncthreads();
        for (int d=tid; d<D_; d+=256){
            float acc = 0.f;
            for (int l=0;l<L_;l++) acc += s_w[l]*curb[l*D_ + d];
            s_wc[d] = acc;
        }
        __syncthreads();
        float wsm = s_red[6];
        for (int d=tid; d<D_; d+=256){
            float acc = wsm * bmt[d];
            for (int k=0;k<D_;k++) acc += s_wc[k] * Wmt[k*D_ + d];
            s_ctx[d] = eluf(acc);
        }
        __syncthreads();
        for (int j=tid; j<G3D_; j+=256){
            float ai = mbih[j], ah = mbhh[j];
            const float* wi = mWih + (size_t)j*D_;
            const float* wh = mWhh + (size_t)j*D_;
            for (int k=0;k<D_;k++){ ai += s_ctx[k]*wi[k]; ah += s_mf[k]*wh[k]; }
            s_gi[j] = ai; s_gh[j] = ah;
        }
        __syncthreads();
        for (int d=tid; d<D_; d+=256){
            float rr = sigmf(s_gi[d] + s_gh[d]);
            float zz = sigmf(s_gi[D_+d] + s_gh[D_+d]);
            float nn = tanhf(s_gi[2*D_+d] + rr*s_gh[2*D_+d]);
            float nm = (1.f-zz)*nn + zz*s_mf[d];
            s_mf[d] = nm; s_act[d] = fmaxf(nm, 0.f);
        }
        __syncthreads();
    }
    const float dd = (float)(R_ - 2);
    float p = 0.f;
    for (int d=tid; d<D_; d+=256){
        float acc = bme[d];
        for (int k=0;k<D_;k++){
            float mf = s_mf[k];
            acc += mf * Wme[k*D_ + d];
            acc += (mf + dd) * Wme[(D_+k)*D_ + d];
        }
        p += acc * Wout[d];
    }
    float o = blockReduceSum(p, s_red);
    if (tid==0){
        o += bout[0];
        if (*amtag == FP32TAG) ((float*)out)[b] = o;
        else ((bf16*)out)[b] = __float2bfloat16(o);
    }
}

extern "C" void kernel_launch(void* const* d_in, const int* in_sizes, int n_in,
                              void* d_out, int out_size, void* d_ws, size_t ws_size,
                              hipStream_t stream) {
    const int* adl = (const int*)d_in[2];
    const int* bdl = (const int*)d_in[3];
    const unsigned* amtag = (const unsigned*)d_in[4];

    // converted segments (d_in index -> element count); Wih(13)/Whh(14) handled by k_transpose
    static const int srcidx[NSEG] = {0,1,4,5,6,7,8,9,10,11,12,15,16,17,18,19,20,21,22,23,24,25,26,27,28};
    static const int segsz[NSEG]  = {638976,327680,16384,7800,200,9800,200,1200,3,120000,600,
                                     1800,1800,400,1,40000,200,120000,120000,600,600,80000,200,200,1};
    CvtArgs ca;
    int ofs[NSEG+1]; ofs[0] = 0;
    for (int i=0;i<NSEG;i++){ ca.src[i] = d_in[srcidx[i]]; ca.ofs[i] = ofs[i]; ofs[i+1] = ofs[i] + segsz[i]; }
    ca.ofs[NSEG] = ofs[NSEG];
    const int total = ofs[NSEG];           // 1488645

    float* ws   = (float*)d_ws;
    float* conv = ws;
    float* Ti   = conv + ((total + 7) & ~7);
    float* Th   = Ti + R_*D_*G3D_;
    float* h    = Th + R_*D_*G3D_;
    float* cur  = h + BLD_;
    float* ctx  = cur + BLD_;
    float* s1   = ctx + BLD_;
    float* tb   = s1 + BL_;
    // total ws: ~48.3 MB

    const float* c_atom  = conv + ofs[0];
    const float* c_bond  = conv + ofs[1];
    const float* c_amask = conv + ofs[2];
    const float* c_Watom = conv + ofs[3];
    const float* c_batom = conv + ofs[4];
    const float* c_Wnei  = conv + ofs[5];
    const float* c_bnei  = conv + ofs[6];
    const float* c_Walign= conv + ofs[7];
    const float* c_balign= conv + ofs[8];
    const float* c_Watt  = conv + ofs[9];
    const float* c_batt  = conv + ofs[10];
    const float* c_bih   = conv + ofs[11];
    const float* c_bhh   = conv + ofs[12];
    const float* c_Wma   = conv + ofs[13];
    const float* c_bma   = conv + ofs[14];
    const float* c_Wmt   = conv + ofs[15];
    const float* c_bmt   = conv + ofs[16];
    const float* c_mWih  = conv + ofs[17];
    const float* c_mWhh  = conv + ofs[18];
    const float* c_mbih  = conv + ofs[19];
    const float* c_mbhh  = conv + ofs[20];
    const float* c_Wme   = conv + ofs[21];
    const float* c_bme   = conv + ofs[22];
    const float* c_Wout  = conv + ofs[23];
    const float* c_bout  = conv + ofs[24];

    k_convert<<<(total + 255)/256, 256, 0, stream>>>(ca, conv, amtag, total);
    k_transpose<<<(R_*D_*G3D_ + 255)/256, 256, 0, stream>>>(d_in[13], d_in[14], Ti, Th, amtag);
    k_atomfeat<<<BLD_/256, 256, 0, stream>>>(c_atom, c_Watom, c_batom, h, cur);

    for (int r=0; r<R_; r++){
        k_dots<<<BL_/4, 256, 0, stream>>>(cur, c_Walign, r, s1, tb);
        k_attn_ctx<<<BL_, 64, 0, stream>>>(cur, s1, tb, adl, bdl, c_atom, c_bond,
                                           c_Wnei, c_bnei, c_Walign, c_balign, c_Watt, c_batt, r, ctx);
        k_gruf<<<BL_/8, 256, 0, stream>>>(ctx, h, cur, Ti, Th, c_bih, c_bhh, r);
    }

    k_mol<<<B_, 256, 0, stream>>>(cur, c_amask, c_Wma, c_bma, c_Wmt, c_bmt,
                                  c_mWih, c_mWhh, c_mbih, c_mbhh, c_Wme, c_bme, c_Wout, c_bout,
                                  d_out, amtag);
}

// Round 4
// 1239.319 us; speedup vs baseline: 1.1710x; 1.1710x over previous
//
#include <hip/hip_runtime.h>
#include <hip/hip_bf16.h>
#include <math.h>

#define B_ 128
#define L_ 128
#define N_ 6
#define FA_ 39
#define FB_ 10
#define D_ 200
#define MB_ 256
#define R_ 3
#define T_ 2
#define NEGV -9e8f
#define BL_ (B_*L_)        // 16384
#define BLD_ (BL_*D_)      // 3276800
#define G3D_ (3*D_)        // 600
#define FP32TAG 0x3F800000u
#define CTXA 16            // atoms per block in k_ctxgemm

typedef __hip_bfloat16 bf16;

__device__ __forceinline__ float b2f(const bf16 x){ return __bfloat162float(x); }
__device__ __forceinline__ float lreluf(float x){ return x>=0.f ? x : 0.01f*x; }
__device__ __forceinline__ float eluf(float x){ return x>0.f ? x : expm1f(x); }
__device__ __forceinline__ float sigmf(float x){ return 1.f/(1.f+expf(-x)); }

#define NSEG 25
struct CvtArgs { const void* src[NSEG]; int ofs[NSEG+1]; };

// canonicalize all float inputs (bf16 OR fp32 storage) to fp32 in ws
__global__ void k_convert(CvtArgs c, float* __restrict__ dst, const unsigned* __restrict__ amtag, int total){
    int i = blockIdx.x*blockDim.x + threadIdx.x;
    if (i >= total) return;
    bool f32 = (*amtag == FP32TAG);
    int s = 0;
    while (i >= c.ofs[s+1]) s++;
    int j = i - c.ofs[s];
    dst[i] = f32 ? ((const float*)c.src[s])[j] : b2f(((const bf16*)c.src[s])[j]);
}

// transpose GRU weights to [r][k][j] fp32 for coalesced gate-GEMM loads (dual-dtype read)
__global__ void k_transpose(const void* __restrict__ Wih, const void* __restrict__ Whh,
                            float* __restrict__ Ti, float* __restrict__ Th,
                            const unsigned* __restrict__ amtag){
    int idx = blockIdx.x*blockDim.x + threadIdx.x;
    if (idx >= R_*D_*G3D_) return;       // 360000
    bool f32 = (*amtag == FP32TAG);
    int j  = idx % G3D_;
    int rk = idx / G3D_;
    int k  = rk % D_;
    int r  = rk / D_;
    size_t si = ((size_t)r*G3D_ + j)*D_ + k;
    Ti[idx] = f32 ? ((const float*)Wih)[si] : b2f(((const bf16*)Wih)[si]);
    Th[idx] = f32 ? ((const float*)Whh)[si] : b2f(((const bf16*)Whh)[si]);
}

// atom_feature = lrelu(atom_list @ W_atom + b_atom); h = cur = atom_feature
__global__ void k_atomfeat(const float* __restrict__ atom_list, const float* __restrict__ W_atom,
                           const float* __restrict__ b_atom, float* __restrict__ h, float* __restrict__ cur){
    int idx = blockIdx.x*blockDim.x + threadIdx.x;
    if (idx >= BLD_) return;
    int d = idx % D_;
    int al = idx / D_;
    const float* arow = atom_list + (size_t)al*FA_;
    float acc = b_atom[d];
    for (int k=0;k<FA_;k++) acc += arow[k] * W_atom[k*D_ + d];
    float v = lreluf(acc);
    h[idx] = v; cur[idx] = v;
}

// per-atom dots with W_align[r]: s1 = cur . Wa[0:D], tb = cur . Wa[D:2D]
__global__ void k_dots(const float* __restrict__ cur, const float* __restrict__ W_align, int r,
                       float* __restrict__ s1, float* __restrict__ tb){
    int wave = (blockIdx.x*blockDim.x + threadIdx.x) >> 6;
    int lane = threadIdx.x & 63;
    if (wave >= BL_) return;
    const float* Wa = W_align + r*2*D_;
    const float* row = cur + (size_t)wave*D_;
    float a1 = 0.f, a2 = 0.f;
    for (int k=lane; k<D_; k+=64){
        float c = row[k];
        a1 += c * Wa[k];
        a2 += c * Wa[D_+k];
    }
    for (int o=32;o>0;o>>=1){ a1 += __shfl_xor(a1,o); a2 += __shfl_xor(a2,o); }
    if (lane==0){ s1[wave]=a1; tb[wave]=a2; }
}

// attention: (round-0 on-the-fly neighbor features) + softmax + weighted neighbor sum
// one wave (64 threads) per atom; writes wnei[BL,D] and wsum[BL]
__global__ void __launch_bounds__(64) k_attn(
        const float* __restrict__ cur, const float* __restrict__ s1, const float* __restrict__ tb,
        const int* __restrict__ adl, const int* __restrict__ bdl,
        const float* __restrict__ atom_list, const float* __restrict__ bond_list,
        const float* __restrict__ W_nei, const float* __restrict__ b_nei,
        const float* __restrict__ W_align, const float* __restrict__ b_align, int r,
        float* __restrict__ wnei, float* __restrict__ wsum){
    int al = blockIdx.x;
    int lane = threadIdx.x;
    int bi = al >> 7;            // / L_
    __shared__ float s_nei[N_][D_];
    __shared__ float s_s2[N_];

    int idxn[N_]; bool pad[N_];
    for (int n=0;n<N_;n++){ idxn[n] = adl[al*N_ + n]; pad[n] = (idxn[n] == L_-1); }

    if (r == 0){
        for (int j = lane; j < N_*D_; j += 64){
            int n = j / D_, d = j - n*D_;
            int a  = idxn[n];
            int bd = bdl[al*N_ + n];
            const float* arow = atom_list + ((size_t)bi*L_ + a)*FA_;
            const float* brow = bond_list + ((size_t)bi*MB_ + bd)*FB_;
            float acc = b_nei[d];
            for (int k=0;k<FA_;k++) acc += arow[k] * W_nei[k*D_ + d];
            for (int k=0;k<FB_;k++) acc += brow[k] * W_nei[(FA_+k)*D_ + d];
            s_nei[n][d] = lreluf(acc);
        }
        __syncthreads();
        const float* Wab = W_align + (2*r+1)*D_;   // bottom half of W_align[r]
        for (int n=0;n<N_;n++){
            float acc = 0.f;
            for (int d=lane; d<D_; d+=64) acc += s_nei[n][d] * Wab[d];
            for (int o=32;o>0;o>>=1) acc += __shfl_xor(acc,o);
            if (lane==0) s_s2[n] = acc;
        }
        __syncthreads();
    } else {
        if (lane < N_) s_s2[lane] = tb[bi*L_ + idxn[lane]];
        __syncthreads();
    }

    float s1v = s1[al];
    float bav = b_align[r];
    float a[N_]; float mx = -1e30f;
    for (int n=0;n<N_;n++){
        float v = lreluf(s1v + s_s2[n] + bav);
        if (pad[n]) v += NEGV;
        a[n] = v; mx = fmaxf(mx, v);
    }
    float w[N_]; float se = 0.f;
    for (int n=0;n<N_;n++){ float e = expf(a[n]-mx); w[n]=e; se += e; }
    float inv = 1.f/se; float wsv = 0.f;
    for (int n=0;n<N_;n++){ w[n] = pad[n] ? 0.f : w[n]*inv; wsv += w[n]; }

    if (r == 0){
        for (int d=lane; d<D_; d+=64){
            float acc = 0.f;
            for (int n=0;n<N_;n++) acc += w[n] * s_nei[n][d];
            wnei[(size_t)al*D_ + d] = acc;
        }
    } else {
        for (int d=lane; d<D_; d+=64){
            float acc = 0.f;
            for (int n=0;n<N_;n++) acc += w[n] * cur[((size_t)bi*L_ + idxn[n])*D_ + d];
            wnei[(size_t)al*D_ + d] = acc;
        }
    }
    if (lane==0) wsum[al] = wsv;
}

// ctx = elu(wnei @ W_attend[r] + wsum * b_attend[r]) — CTXA atom rows per block,
// W_attend load amortized over CTXA register accumulators
__global__ void __launch_bounds__(256) k_ctxgemm(const float* __restrict__ wnei,
        const float* __restrict__ wsum,
        const float* __restrict__ W_attend, const float* __restrict__ b_attend, int r,
        float* __restrict__ ctx){
    int tid = threadIdx.x;
    int al0 = blockIdx.x * CTXA;
    __shared__ float s_x[CTXA][D_];
    __shared__ float s_ws[CTXA];
    for (int i = tid; i < CTXA*D_; i += 256){
        int a = i / D_, d = i - a*D_;
        s_x[a][d] = wnei[(size_t)(al0+a)*D_ + d];
    }
    if (tid < CTXA) s_ws[tid] = wsum[al0 + tid];
    __syncthreads();
    int j = tid;
    if (j < D_){
        const float* W = W_attend + (size_t)r*D_*D_;
        float bv = b_attend[r*D_ + j];
        float acc[CTXA];
        #pragma unroll
        for (int a=0;a<CTXA;a++) acc[a] = 0.f;
        for (int k=0;k<D_;k++){
            float wv = W[k*D_ + j];
            #pragma unroll
            for (int a=0;a<CTXA;a++) acc[a] += s_x[a][k] * wv;
        }
        #pragma unroll
        for (int a=0;a<CTXA;a++)
            ctx[(size_t)(al0+a)*D_ + j] = eluf(acc[a] + s_ws[a]*bv);
    }
}

// fused GRU: gates GEMM (transposed weights) + combine. 8 atoms per 256-thread block.
__global__ void __launch_bounds__(256) k_gruf(const float* __restrict__ ctx, float* __restrict__ h,
        float* __restrict__ cur,
        const float* __restrict__ Ti, const float* __restrict__ Th,
        const float* __restrict__ bih, const float* __restrict__ bhh, int r){
    int tid = threadIdx.x;
    int al0 = blockIdx.x * 8;
    __shared__ float s_x[8][D_], s_h[8][D_];
    __shared__ float s_gi[8][G3D_], s_gh[8][G3D_];
    for (int i = tid; i < 8*D_; i += 256){
        int a = i / D_, d = i - a*D_;
        s_x[a][d] = ctx[(size_t)(al0+a)*D_ + d];
        s_h[a][d] = h[(size_t)(al0+a)*D_ + d];
    }
    __syncthreads();
    const float* ti = Ti + (size_t)r*D_*G3D_;
    const float* th = Th + (size_t)r*D_*G3D_;
    for (int j = tid; j < G3D_; j += 256){
        float ai[8], ah[8];
        float bi_ = bih[r*G3D_+j], bh_ = bhh[r*G3D_+j];
        #pragma unroll
        for (int a=0;a<8;a++){ ai[a]=bi_; ah[a]=bh_; }
        for (int k=0;k<D_;k++){
            float wiv = ti[(size_t)k*G3D_ + j];
            float whv = th[(size_t)k*G3D_ + j];
            #pragma unroll
            for (int a=0;a<8;a++){ ai[a] += s_x[a][k]*wiv; ah[a] += s_h[a][k]*whv; }
        }
        #pragma unroll
        for (int a=0;a<8;a++){ s_gi[a][j]=ai[a]; s_gh[a][j]=ah[a]; }
    }
    __syncthreads();
    for (int i = tid; i < 8*D_; i += 256){
        int a = i / D_, d = i - a*D_;
        float rr = sigmf(s_gi[a][d] + s_gh[a][d]);
        float zz = sigmf(s_gi[a][D_+d] + s_gh[a][D_+d]);
        float nn = tanhf(s_gi[a][2*D_+d] + rr*s_gh[a][2*D_+d]);
        float hv = s_h[a][d];
        float hn = (1.f-zz)*nn + zz*hv;
        h[(size_t)(al0+a)*D_+d] = hn;
        cur[(size_t)(al0+a)*D_+d] = fmaxf(hn, 0.f);
    }
}

__device__ __forceinline__ float blockReduceSum(float v, float* s_red){
    for (int o=32;o>0;o>>=1) v += __shfl_xor(v,o);
    int lane = threadIdx.x & 63, wid = threadIdx.x >> 6;
    __syncthreads();
    if (lane==0) s_red[wid] = v;
    __syncthreads();
    float r = s_red[0];
    int nw = blockDim.x >> 6;
    for (int i=1;i<nw;i++) r += s_red[i];
    return r;
}

// molecule phase: pooling, T mol-attention+GRU steps, output head. One block per molecule.
__global__ void __launch_bounds__(256) k_mol(const float* __restrict__ cur, const float* __restrict__ atom_mask,
    const float* __restrict__ Wma, const float* __restrict__ bma,
    const float* __restrict__ Wmt, const float* __restrict__ bmt,
    const float* __restrict__ mWih, const float* __restrict__ mWhh,
    const float* __restrict__ mbih, const float* __restrict__ mbhh,
    const float* __restrict__ Wme, const float* __restrict__ bme,
    const float* __restrict__ Wout, const float* __restrict__ bout,
    void* __restrict__ out, const unsigned* __restrict__ amtag){
    int b = blockIdx.x, tid = threadIdx.x;
    __shared__ float s_am[L_], s_neg[L_], s_mf[D_], s_act[D_], s_sc[L_], s_w[L_];
    __shared__ float s_wc[D_], s_ctx[D_], s_gi[G3D_], s_gh[G3D_], s_red[8];
    const float* curb = cur + (size_t)b*L_*D_;
    if (tid < L_){
        float am = atom_mask[b*L_ + tid];
        s_am[tid] = am;
        s_neg[tid] = (am == 0.f) ? NEGV : 0.f;
    }
    __syncthreads();
    for (int d=tid; d<D_; d+=256){
        float acc = 0.f;
        for (int l=0;l<L_;l++) acc += curb[l*D_ + d] * s_am[l];
        s_mf[d] = acc; s_act[d] = fmaxf(acc, 0.f);
    }
    __syncthreads();
    for (int t=0;t<T_;t++){
        float p = 0.f;
        for (int d=tid; d<D_; d+=256) p += s_act[d] * Wma[d];
        float s1 = blockReduceSum(p, s_red);
        if (tid < L_){
            const float* row = curb + tid*D_;
            float sc = 0.f;
            for (int d=0; d<D_; d++) sc += row[d] * Wma[D_+d];
            sc = lreluf(s1 + sc + bma[0]);
            s_sc[tid] = sc + s_neg[tid];
        }
        __syncthreads();
        if (tid==0){ float mx=-1e30f; for (int l=0;l<L_;l++) mx=fmaxf(mx,s_sc[l]); s_red[4]=mx; }
        __syncthreads();
        if (tid < L_) s_w[tid] = expf(s_sc[tid] - s_red[4]);
        __syncthreads();
        if (tid==0){ float sm=0.f; for (int l=0;l<L_;l++) sm+=s_w[l]; s_red[5]=sm; }
        __syncthreads();
        if (tid < L_) s_w[tid] = s_w[tid]/s_red[5]*s_am[tid];
        __syncthreads();
        if (tid==0){ float sm=0.f; for (int l=0;l<L_;l++) sm+=s_w[l]; s_red[6]=sm; }
        __syncthreads();
        for (int d=tid; d<D_; d+=256){
            float acc = 0.f;
            for (int l=0;l<L_;l++) acc += s_w[l]*curb[l*D_ + d];
            s_wc[d] = acc;
        }
        __syncthreads();
        float wsm = s_red[6];
        for (int d=tid; d<D_; d+=256){
            float acc = wsm * bmt[d];
            for (int k=0;k<D_;k++) acc += s_wc[k] * Wmt[k*D_ + d];
            s_ctx[d] = eluf(acc);
        }
        __syncthreads();
        for (int j=tid; j<G3D_; j+=256){
            float ai = mbih[j], ah = mbhh[j];
            const float* wi = mWih + (size_t)j*D_;
            const float* wh = mWhh + (size_t)j*D_;
            for (int k=0;k<D_;k++){ ai += s_ctx[k]*wi[k]; ah += s_mf[k]*wh[k]; }
            s_gi[j] = ai; s_gh[j] = ah;
        }
        __syncthreads();
        for (int d=tid; d<D_; d+=256){
            float rr = sigmf(s_gi[d] + s_gh[d]);
            float zz = sigmf(s_gi[D_+d] + s_gh[D_+d]);
            float nn = tanhf(s_gi[2*D_+d] + rr*s_gh[2*D_+d]);
            float nm = (1.f-zz)*nn + zz*s_mf[d];
            s_mf[d] = nm; s_act[d] = fmaxf(nm, 0.f);
        }
        __syncthreads();
    }
    const float dd = (float)(R_ - 2);
    float p = 0.f;
    for (int d=tid; d<D_; d+=256){
        float acc = bme[d];
        for (int k=0;k<D_;k++){
            float mf = s_mf[k];
            acc += mf * Wme[k*D_ + d];
            acc += (mf + dd) * Wme[(D_+k)*D_ + d];
        }
        p += acc * Wout[d];
    }
    float o = blockReduceSum(p, s_red);
    if (tid==0){
        o += bout[0];
        if (*amtag == FP32TAG) ((float*)out)[b] = o;
        else ((bf16*)out)[b] = __float2bfloat16(o);
    }
}

extern "C" void kernel_launch(void* const* d_in, const int* in_sizes, int n_in,
                              void* d_out, int out_size, void* d_ws, size_t ws_size,
                              hipStream_t stream) {
    const int* adl = (const int*)d_in[2];
    const int* bdl = (const int*)d_in[3];
    const unsigned* amtag = (const unsigned*)d_in[4];

    static const int srcidx[NSEG] = {0,1,4,5,6,7,8,9,10,11,12,15,16,17,18,19,20,21,22,23,24,25,26,27,28};
    static const int segsz[NSEG]  = {638976,327680,16384,7800,200,9800,200,1200,3,120000,600,
                                     1800,1800,400,1,40000,200,120000,120000,600,600,80000,200,200,1};
    CvtArgs ca;
    int ofs[NSEG+1]; ofs[0] = 0;
    for (int i=0;i<NSEG;i++){ ca.src[i] = d_in[srcidx[i]]; ca.ofs[i] = ofs[i]; ofs[i+1] = ofs[i] + segsz[i]; }
    ca.ofs[NSEG] = ofs[NSEG];
    const int total = ofs[NSEG];           // 1488645

    float* ws   = (float*)d_ws;
    float* conv = ws;
    float* Ti   = conv + ((total + 7) & ~7);
    float* Th   = Ti + R_*D_*G3D_;
    float* h    = Th + R_*D_*G3D_;
    float* cur  = h + BLD_;
    float* ctx  = cur + BLD_;
    float* wnei = ctx + BLD_;
    float* s1   = wnei + BLD_;
    float* tb   = s1 + BL_;
    float* wsum = tb + BL_;
    // total ws: ~61.6 MB

    const float* c_atom  = conv + ofs[0];
    const float* c_bond  = conv + ofs[1];
    const float* c_amask = conv + ofs[2];
    const float* c_Watom = conv + ofs[3];
    const float* c_batom = conv + ofs[4];
    const float* c_Wnei  = conv + ofs[5];
    const float* c_bnei  = conv + ofs[6];
    const float* c_Walign= conv + ofs[7];
    const float* c_balign= conv + ofs[8];
    const float* c_Watt  = conv + ofs[9];
    const float* c_batt  = conv + ofs[10];
    const float* c_bih   = conv + ofs[11];
    const float* c_bhh   = conv + ofs[12];
    const float* c_Wma   = conv + ofs[13];
    const float* c_bma   = conv + ofs[14];
    const float* c_Wmt   = conv + ofs[15];
    const float* c_bmt   = conv + ofs[16];
    const float* c_mWih  = conv + ofs[17];
    const float* c_mWhh  = conv + ofs[18];
    const float* c_mbih  = conv + ofs[19];
    const float* c_mbhh  = conv + ofs[20];
    const float* c_Wme   = conv + ofs[21];
    const float* c_bme   = conv + ofs[22];
    const float* c_Wout  = conv + ofs[23];
    const float* c_bout  = conv + ofs[24];

    k_convert<<<(total + 255)/256, 256, 0, stream>>>(ca, conv, amtag, total);
    k_transpose<<<(R_*D_*G3D_ + 255)/256, 256, 0, stream>>>(d_in[13], d_in[14], Ti, Th, amtag);
    k_atomfeat<<<BLD_/256, 256, 0, stream>>>(c_atom, c_Watom, c_batom, h, cur);

    for (int r=0; r<R_; r++){
        k_dots<<<BL_/4, 256, 0, stream>>>(cur, c_Walign, r, s1, tb);
        k_attn<<<BL_, 64, 0, stream>>>(cur, s1, tb, adl, bdl, c_atom, c_bond,
                                       c_Wnei, c_bnei, c_Walign, c_balign, r, wnei, wsum);
        k_ctxgemm<<<BL_/CTXA, 256, 0, stream>>>(wnei, wsum, c_Watt, c_batt, r, ctx);
        k_gruf<<<BL_/8, 256, 0, stream>>>(ctx, h, cur, Ti, Th, c_bih, c_bhh, r);
    }

    k_mol<<<B_, 256, 0, stream>>>(cur, c_amask, c_Wma, c_bma, c_Wmt, c_bmt,
                                  c_mWih, c_mWhh, c_mbih, c_mbhh, c_Wme, c_bme, c_Wout, c_bout,
                                  d_out, amtag);
}